// Round 8
// baseline (103.653 us; speedup 1.0000x reference)
//
#include <hip/hip_runtime.h>

#define DIM_W 160
#define DIM_H 192
#define DIM_D 160
#define DIM_B 2

constexpr int TW = 16;      // output tile width
constexpr int TH = 48;      // output tile height (P=3 px/thread in H)
constexpr int CH = 19;      // depth outputs per chunk (27 slices = 3 x 9)
constexpr int NCH = 9;      // ceil(160/19)
constexpr int RH = TH + 8;  // 56 region rows
constexpr float INV_K = 1.0f / 729.0f;
constexpr double NTOT = 9830400.0;

typedef unsigned int u32;
typedef __attribute__((address_space(1))) const u32 gu32;
typedef __attribute__((address_space(3))) u32 lu32;

__global__ void init_kernel(float* out, float* ws) {
    out[0] = 0.0f;
    ws[0] = 0.0f; ws[1] = 0.0f; ws[2] = 0.0f; ws[3] = 0.0f;
}

__device__ __forceinline__ int clampD(int s) {
    return s < 0 ? 0 : (s > DIM_D - 1 ? DIM_D - 1 : s);
}

__global__ __launch_bounds__(256)
void lncc3d_kernel(const float* __restrict__ I,
                   const float* __restrict__ T,
                   const float* __restrict__ zsrc,
                   float* __restrict__ out)
{
    // slice region, glds-staged: row = 128B; logical f4 q of row r at physical (q+r)&7
    __shared__ __align__(16) float sR[2][2][RH][32];
    // W-sums (I,T,II,TT): float4, column rotated (c+row)&15
    __shared__ __align__(16) float4 wA[RH][16];
    // W-sums IT, transposed [w][row], stride 60
    __shared__ __align__(16) float  wB[16][60];
    __shared__ float red[4];

    const int tid  = threadIdx.x;
    const int lane = tid & 63;
    const int wid  = tid >> 6;
    const int wo   = tid & 15;
    const int hb   = (tid >> 4) * 3;      // 0,3,...,45

    const int bw = blockIdx.x, bh = blockIdx.y, bz = blockIdx.z;
    const int b  = bz / NCH;
    const int c  = bz - b * NCH;
    const int w0 = bw * TW, h0 = bh * TH, d0 = c * CH;
    const int dEnd = min(d0 + CH, DIM_D);

    const int plane = DIM_H * DIM_W;
    const int fld  = wid >> 1;            // 0: field I, 1: field T
    const int khi  = wid & 1;             // chunk set {4,5,6} vs {0,1,2,3}
    const int nck  = khi ? 3 : 4;         // glds per wave per slice
    const float* Fb = (fld ? T : I) + (size_t)b * DIM_D * plane;

    // per-lane glds source offsets (f4 rotation folded into source address)
    int boff[4], crw[4];
#pragma unroll
    for (int i = 0; i < 4; ++i) {
        const int ck  = khi ? (4 + i) : i;
        const int row = 8 * ck + (lane >> 3);
        const int pf4 = lane & 7;
        const int lf4 = (pf4 - row) & 7;
        const int gh  = h0 - 4 + row;
        const int gw  = w0 - 8 + (lf4 << 2);
        crw[i]  = 8 * ck;
        boff[i] = (i < nck && gh >= 0 && gh < DIM_H && gw >= 0 && gw <= DIM_W - 4)
                  ? (gh * DIM_W + gw) : -1;
    }

    auto issue = [&](int sc, int buf) {
        const float* Fs = Fb + (size_t)sc * plane;
#pragma unroll
        for (int i = 0; i < 4; ++i) {
            if (i < nck) {
                const float* gp = (boff[i] >= 0) ? (Fs + boff[i]) : zsrc;
                __builtin_amdgcn_global_load_lds((gu32*)gp, (lu32*)&sR[buf][fld][crw[i]][0],
                                                 16, 0, 0);
            }
        }
    };

    // D-rings (slot = static J) + running sums, 5 fields x 3 px
    float rgI[3][9], rgT[3][9], rgII[3][9], rgTT[3][9], rgIT[3][9];
    float rnI[3], rnT[3], rnII[3], rnTT[3], rnIT[3];
#pragma unroll
    for (int p = 0; p < 3; ++p) {
        rnI[p] = rnT[p] = rnII[p] = rnTT[p] = rnIT[p] = 0.0f;
#pragma unroll
        for (int q = 0; q < 9; ++q) {
            rgI[p][q] = rgT[p][q] = rgII[p][q] = rgTT[p][q] = rgIT[p][q] = 0.0f;
        }
    }
    float acc = 0.0f;

    const int sStart = d0 - 4;
    int cur = 0;

    // ---- prologue: stage sStart -> buf0, sStart+1 -> buf1 ----
    issue(clampD(sStart), 0);
    issue(clampD(sStart + 1), 1);
    if (khi) { asm volatile("s_waitcnt vmcnt(3)" ::: "memory"); }
    else     { asm volatile("s_waitcnt vmcnt(4)" ::: "memory"); }
    __builtin_amdgcn_s_barrier();

    for (int t = 0; t < 3; ++t) {
        const int t9 = t * 9;
#pragma unroll
        for (int j = 0; j < 9; ++j) {
            const int s  = sStart + t9 + j;
            const bool vs = (s >= 0) && (s < DIM_D);

            // ---- stage 1: 9-wide W sums on sR[cur] (224 producers) ----
            if (vs && tid < 224) {
                const int r = tid >> 2;       // 0..55
                const int g = tid & 3;
                const float* rIp = &sR[cur][0][r][0];
                const float* rTp = &sR[cur][1][r][0];
                const int q0 = ((g + 1 + r) & 7) << 2;
                const int q1 = ((g + 2 + r) & 7) << 2;
                const int q2 = ((g + 3 + r) & 7) << 2;
                const float4 ia  = *(const float4*)(rIp + q0);
                const float4 ib4 = *(const float4*)(rIp + q1);
                const float4 ic4 = *(const float4*)(rIp + q2);
                const float4 ta  = *(const float4*)(rTp + q0);
                const float4 tb4 = *(const float4*)(rTp + q1);
                const float4 tc4 = *(const float4*)(rTp + q2);
                const float iv[12] = {ia.x, ia.y, ia.z, ia.w, ib4.x, ib4.y, ib4.z, ib4.w,
                                      ic4.x, ic4.y, ic4.z, ic4.w};
                const float tv[12] = {ta.x, ta.y, ta.z, ta.w, tb4.x, tb4.y, tb4.z, tb4.w,
                                      tc4.x, tc4.y, tc4.z, tc4.w};
                float aI = 0.f, aT = 0.f, aII = 0.f, aTT = 0.f, aIT = 0.f;
#pragma unroll
                for (int k = 0; k < 9; ++k) {
                    aI += iv[k]; aT += tv[k];
                    aII = fmaf(iv[k], iv[k], aII);
                    aTT = fmaf(tv[k], tv[k], aTT);
                    aIT = fmaf(iv[k], tv[k], aIT);
                }
                const int c0 = g << 2;
                wA[r][(c0 + r) & 15] = make_float4(aI, aT, aII, aTT);
                wB[c0][r] = aIT;
#pragma unroll
                for (int q = 1; q < 4; ++q) {
                    const float ni = iv[8 + q], oi = iv[q - 1];
                    const float nt = tv[8 + q], ot = tv[q - 1];
                    aI += ni - oi; aT += nt - ot;
                    aII = fmaf(ni, ni, fmaf(oi, -oi, aII));
                    aTT = fmaf(nt, nt, fmaf(ot, -ot, aTT));
                    aIT = fmaf(ni, nt, fmaf(oi, -ot, aIT));
                    wA[r][(c0 + q + r) & 15] = make_float4(aI, aT, aII, aTT);
                    wB[c0 + q][r] = aIT;
                }
            }
            asm volatile("s_waitcnt lgkmcnt(0)" ::: "memory");
            __builtin_amdgcn_s_barrier();   // wA/wB published; sR[cur] reads done

            // ---- issue glds for slice s+2 into sR[cur] ----
            issue(clampD(s + 2), cur);

            // ---- stage 2: 9-tall H sums (3 px sliding), rings slot j, emit ----
            float s2I[3], s2T[3], s2II[3], s2TT[3], s2IT[3];
            if (vs) {
#define RDA(k) wA[hb + (k)][(wo + hb + (k)) & 15]
                const float4 A0 = RDA(0);
                const float4 A1 = RDA(1);
                float sx = A0.x + A1.x, sy = A0.y + A1.y;
                float sz = A0.z + A1.z, sw = A0.w + A1.w;
#pragma unroll
                for (int k = 2; k < 9; ++k) {
                    const float4 Ak = RDA(k);
                    sx += Ak.x; sy += Ak.y; sz += Ak.z; sw += Ak.w;
                }
                s2I[0] = sx; s2T[0] = sy; s2II[0] = sz; s2TT[0] = sw;
                const float4 A9 = RDA(9);
                const float p1x = sx - A0.x + A9.x, p1y = sy - A0.y + A9.y;
                const float p1z = sz - A0.z + A9.z, p1w = sw - A0.w + A9.w;
                s2I[1] = p1x; s2T[1] = p1y; s2II[1] = p1z; s2TT[1] = p1w;
                const float4 A10 = RDA(10);
                s2I[2]  = p1x - A1.x + A10.x;
                s2T[2]  = p1y - A1.y + A10.y;
                s2II[2] = p1z - A1.z + A10.z;
                s2TT[2] = p1w - A1.w + A10.w;
#undef RDA
                // IT sums: rows hb..hb+10 via 7 aligned float2 reads
                const int  base = hb & ~1;
                const bool od   = (hb & 1) != 0;
                const float* wp = &wB[wo][base];
                const float2 e0 = *(const float2*)(wp);
                const float2 e1 = *(const float2*)(wp + 2);
                const float2 e2 = *(const float2*)(wp + 4);
                const float2 e3 = *(const float2*)(wp + 6);
                const float2 e4 = *(const float2*)(wp + 8);
                const float2 e5 = *(const float2*)(wp + 10);
                const float2 e6 = *(const float2*)(wp + 12);
                const float f0 = e0.x, f1 = e0.y, f2 = e1.x, f3 = e1.y;
                const float f4 = e2.x, f5 = e2.y, f6 = e3.x, f7 = e3.y;
                const float f8 = e4.x, f9 = e4.y, f10 = e5.x, f11 = e5.y;
                const float pre9 = f0 + f1 + f2 + f3 + f4 + f5 + f6 + f7 + f8;
                const float it0 = od ? (pre9 - f0 + f9) : pre9;
                const float it1 = it0 - (od ? f1 : f0) + (od ? f10 : f9);
                const float it2 = it1 - (od ? f2 : f1) + (od ? f11 : f10);
                s2IT[0] = it0; s2IT[1] = it1; s2IT[2] = it2;
            } else {
#pragma unroll
                for (int p = 0; p < 3; ++p) {
                    s2I[p] = s2T[p] = s2II[p] = s2TT[p] = s2IT[p] = 0.f;
                }
            }

            const bool em = (s >= d0 + 4) && ((s - 4) < dEnd);
#pragma unroll
            for (int p = 0; p < 3; ++p) {
                rnI[p]  += s2I[p]  - rgI[p][j];  rgI[p][j]  = s2I[p];
                rnT[p]  += s2T[p]  - rgT[p][j];  rgT[p][j]  = s2T[p];
                rnII[p] += s2II[p] - rgII[p][j]; rgII[p][j] = s2II[p];
                rnTT[p] += s2TT[p] - rgTT[p][j]; rgTT[p][j] = s2TT[p];
                rnIT[p] += s2IT[p] - rgIT[p][j]; rgIT[p][j] = s2IT[p];
                if (em) {
                    const float cr  = rnIT[p] - rnI[p] * rnT[p] * INV_K;
                    const float vv  = rnII[p] - rnI[p] * rnI[p] * INV_K;
                    const float tvv = rnTT[p] - rnT[p] * rnT[p] * INV_K;
                    acc += cr * cr * __builtin_amdgcn_rcpf(fmaf(tvv, vv, 1e-5f));
                }
            }

            // ---- certify own glds for slice s+1 landed (s+2's stay in flight) ----
            asm volatile("s_waitcnt lgkmcnt(0)" ::: "memory");
            if (khi) { asm volatile("s_waitcnt vmcnt(3)" ::: "memory"); }
            else     { asm volatile("s_waitcnt vmcnt(4)" ::: "memory"); }
            __builtin_amdgcn_s_barrier();
            cur ^= 1;
        }
    }

    // ---- block reduction ----
#pragma unroll
    for (int off = 32; off > 0; off >>= 1) acc += __shfl_down(acc, off, 64);
    if (lane == 0) red[wid] = acc;
    __syncthreads();
    if (tid == 0) {
        const float bs = red[0] + red[1] + red[2] + red[3];
        atomicAdd(out, bs * (float)(-1.0 / NTOT));
    }
}

extern "C" void kernel_launch(void* const* d_in, const int* in_sizes, int n_in,
                              void* d_out, int out_size, void* d_ws, size_t ws_size,
                              hipStream_t stream) {
    const float* I = (const float*)d_in[0];
    const float* T = (const float*)d_in[1];
    float* out = (float*)d_out;
    float* ws  = (float*)d_ws;

    init_kernel<<<dim3(1), dim3(1), 0, stream>>>(out, ws);

    dim3 grid(DIM_W / TW, DIM_H / TH, DIM_B * NCH); // 10 x 4 x 18 = 720
    dim3 block(256);
    lncc3d_kernel<<<grid, block, 0, stream>>>(I, T, ws, out);
}

// Round 9
// 90.761 us; speedup vs baseline: 1.1420x; 1.1420x over previous
//
#include <hip/hip_runtime.h>

#define DIM_W 160
#define DIM_H 192
#define DIM_D 160
#define DIM_B 2

constexpr int TW = 16;      // output tile width
constexpr int TH = 32;      // output tile height (P=2 px/thread in H)
constexpr int CH = 19;      // depth outputs per chunk (27 slices = 3 x 9)
constexpr int NCH = 9;      // ceil(160/19)
constexpr int RH = TH + 8;  // 40 region rows
constexpr int RWDS = 24;    // region words per row (16 + 4+4 halo)
constexpr float INV_K = 1.0f / 729.0f;
constexpr double NTOT = 9830400.0;

typedef unsigned int u32;
typedef __attribute__((address_space(1))) const u32 gu32;
typedef __attribute__((address_space(3))) u32 lu32;

__global__ void init_kernel(float* out, float* ws) {
    out[0] = 0.0f;
    ws[0] = 0.0f; ws[1] = 0.0f; ws[2] = 0.0f; ws[3] = 0.0f;
}

__device__ __forceinline__ int clampD(int s) {
    return s < 0 ? 0 : (s > DIM_D - 1 ? DIM_D - 1 : s);
}

// pair-sum across the +4-lane stride (row r gets row r+1's value added),
// DPP shift direction resolved at runtime via dirA.
__device__ __forceinline__ float pairsum(float v, bool dirA) {
    const int vi = __builtin_bit_cast(int, v);
    const int aa = __builtin_amdgcn_update_dpp(0, vi, 0x104, 0xF, 0xF, true); // row_shl:4
    const int bb = __builtin_amdgcn_update_dpp(0, vi, 0x114, 0xF, 0xF, true); // row_shr:4
    const float fa = __builtin_bit_cast(float, aa);
    const float fb = __builtin_bit_cast(float, bb);
    return v + (dirA ? fa : fb);
}

__global__ __launch_bounds__(256)
void lncc3d_kernel(const float* __restrict__ I,
                   const float* __restrict__ T,
                   const float* __restrict__ zsrc,
                   float* __restrict__ out)
{
    // slice region: [buf][field][1024 floats] = 40 rows x 24 words + pad (glds tail)
    __shared__ __align__(16) float sR[2][2][1024];
    // per-row W-sums (I,T,II,TT): float4, column rotated (c+row)&15
    __shared__ __align__(16) float4 wA[RH][16];
    // per-row W-sums IT, transposed [w][row], stride 44
    __shared__ __align__(16) float  wB[16][44];
    // pair-row (G2) W-sums: rows (2p,2p+1), 20 pairs
    __shared__ __align__(16) float4 g2A[20][17];
    __shared__ float  g2B[16][22];
    __shared__ float red[4];

    const int tid  = threadIdx.x;
    const int lane = tid & 63;
    const int wid  = tid >> 6;
    const int wo   = tid & 15;
    const int p0   = tid >> 4;            // pair base = hb/2, 0..15
    const int hb   = p0 << 1;

    const int bw = blockIdx.x, bh = blockIdx.y, bz = blockIdx.z;
    const int b  = bz / NCH;
    const int c  = bz - b * NCH;
    const int w0 = bw * TW, h0 = bh * TH, d0 = c * CH;
    const int dEnd = min(d0 + CH, DIM_D);

    const int plane = DIM_H * DIM_W;
    const int fld = wid >> 1;             // 0: field I, 1: field T
    const int khi = wid & 1;              // chunks {2,3} vs {0,1}
    const float* Fb = (fld ? T : I) + (size_t)b * DIM_D * plane;

    // DPP direction probe (wave-uniform)
    const int shp = __builtin_amdgcn_update_dpp(0, lane, 0x104, 0xF, 0xF, true);
    const bool dirA = (__builtin_amdgcn_readfirstlane(shp) == 4);

    // glds mapping: 4 chunks/field of 1024B; 16B-slot s -> (row = s/6, q = s%6)
    int boff[2], ldof[2];
#pragma unroll
    for (int i = 0; i < 2; ++i) {
        const int ck  = (khi << 1) | i;
        const int s16 = ck * 64 + lane;
        const int row = s16 / 6;
        const int q   = s16 - row * 6;
        const int gh  = h0 - 4 + row;
        const int gw  = w0 - 4 + (q << 2);
        ldof[i] = ck << 8;   // floats
        boff[i] = (row < RH && gh >= 0 && gh < DIM_H && gw >= 0 && gw <= DIM_W - 4)
                  ? (gh * DIM_W + gw) : -1;
    }

    auto issue = [&](int sc, int buf) {
        const float* Fs = Fb + (size_t)sc * plane;
#pragma unroll
        for (int i = 0; i < 2; ++i) {
            const float* gp = (boff[i] >= 0) ? (Fs + boff[i]) : zsrc;
            __builtin_amdgcn_global_load_lds((gu32*)gp, (lu32*)&sR[buf][fld][ldof[i]],
                                             16, 0, 0);
        }
    };

    // D-rings (slot = static J) + running sums, 5 fields x 2 px
    float rgI[2][9], rgT[2][9], rgII[2][9], rgTT[2][9], rgIT[2][9];
    float rnI[2], rnT[2], rnII[2], rnTT[2], rnIT[2];
#pragma unroll
    for (int p = 0; p < 2; ++p) {
        rnI[p] = rnT[p] = rnII[p] = rnTT[p] = rnIT[p] = 0.0f;
#pragma unroll
        for (int q = 0; q < 9; ++q) {
            rgI[p][q] = rgT[p][q] = rgII[p][q] = rgTT[p][q] = rgIT[p][q] = 0.0f;
        }
    }
    float acc = 0.0f;

    const int sStart = d0 - 4;
    int cur = 0;

    // ---- prologue ----
    issue(clampD(sStart), 0);
    issue(clampD(sStart + 1), 1);
    asm volatile("s_waitcnt vmcnt(2)" ::: "memory");
    __builtin_amdgcn_s_barrier();

    for (int t = 0; t < 3; ++t) {
        const int t9 = t * 9;
#pragma unroll
        for (int j = 0; j < 9; ++j) {
            const int s  = sStart + t9 + j;
            const bool vs = (s >= 0) && (s < DIM_D);

            // ---- stage 1: 9-wide W sums + G2 pair sums (160 producers) ----
            if (vs && tid < 160) {
                const int r  = tid >> 2;       // 0..39
                const int g  = tid & 3;
                const int c0 = g << 2;
                const float* rIp = &sR[cur][0][r * RWDS];
                const float* rTp = &sR[cur][1][r * RWDS];
                const float4 ia  = *(const float4*)(rIp + c0);
                const float4 ib4 = *(const float4*)(rIp + c0 + 4);
                const float4 ic4 = *(const float4*)(rIp + c0 + 8);
                const float4 ta  = *(const float4*)(rTp + c0);
                const float4 tb4 = *(const float4*)(rTp + c0 + 4);
                const float4 tc4 = *(const float4*)(rTp + c0 + 8);
                const float iv[12] = {ia.x, ia.y, ia.z, ia.w, ib4.x, ib4.y, ib4.z, ib4.w,
                                      ic4.x, ic4.y, ic4.z, ic4.w};
                const float tv[12] = {ta.x, ta.y, ta.z, ta.w, tb4.x, tb4.y, tb4.z, tb4.w,
                                      tc4.x, tc4.y, tc4.z, tc4.w};
                float vI[4], vT[4], vII[4], vTT[4], vIT[4];
                {
                    float aI = 0.f, aT = 0.f, aII = 0.f, aTT = 0.f, aIT = 0.f;
#pragma unroll
                    for (int k = 0; k < 9; ++k) {
                        aI += iv[k]; aT += tv[k];
                        aII = fmaf(iv[k], iv[k], aII);
                        aTT = fmaf(tv[k], tv[k], aTT);
                        aIT = fmaf(iv[k], tv[k], aIT);
                    }
                    vI[0] = aI; vT[0] = aT; vII[0] = aII; vTT[0] = aTT; vIT[0] = aIT;
#pragma unroll
                    for (int q = 1; q < 4; ++q) {
                        const float ni = iv[8 + q], oi = iv[q - 1];
                        const float nt = tv[8 + q], ot = tv[q - 1];
                        aI += ni - oi; aT += nt - ot;
                        aII = fmaf(ni, ni, fmaf(oi, -oi, aII));
                        aTT = fmaf(nt, nt, fmaf(ot, -ot, aTT));
                        aIT = fmaf(ni, nt, fmaf(oi, -ot, aIT));
                        vI[q] = aI; vT[q] = aT; vII[q] = aII; vTT[q] = aTT; vIT[q] = aIT;
                    }
                }
                const bool ev = ((r & 1) == 0);
                const int  r2 = r >> 1;
#pragma unroll
                for (int q = 0; q < 4; ++q) {
                    wA[r][(c0 + q + r) & 15] = make_float4(vI[q], vT[q], vII[q], vTT[q]);
                    wB[c0 + q][r] = vIT[q];
                    const float gI  = pairsum(vI[q],  dirA);
                    const float gT  = pairsum(vT[q],  dirA);
                    const float gII = pairsum(vII[q], dirA);
                    const float gTT = pairsum(vTT[q], dirA);
                    const float gIT = pairsum(vIT[q], dirA);
                    if (ev) {
                        g2A[r2][c0 + q] = make_float4(gI, gT, gII, gTT);
                        g2B[c0 + q][r2] = gIT;
                    }
                }
            }
            asm volatile("s_waitcnt lgkmcnt(0)" ::: "memory");
            __builtin_amdgcn_s_barrier();   // wA/wB/g2 published; sR[cur] reads done

            // ---- issue glds for slice s+2 into sR[cur] ----
            issue(clampD(s + 2), cur);

            // ---- stage 2: H sums via G2 (2 px), rings slot j, emit ----
            float s2I0, s2T0, s2II0, s2TT0, s2IT0, s2I1, s2T1, s2II1, s2TT1, s2IT1;
            if (vs) {
                const float4 G0 = g2A[p0][wo];
                const float4 G1 = g2A[p0 + 1][wo];
                const float4 G2_ = g2A[p0 + 2][wo];
                const float4 G3 = g2A[p0 + 3][wo];
                const float4 R8 = wA[hb + 8][(wo + hb + 8) & 15];
                const float4 R0 = wA[hb][(wo + hb) & 15];
                const float4 R9 = wA[hb + 9][(wo + hb + 9) & 15];
                s2I0  = G0.x + G1.x + G2_.x + G3.x + R8.x;
                s2T0  = G0.y + G1.y + G2_.y + G3.y + R8.y;
                s2II0 = G0.z + G1.z + G2_.z + G3.z + R8.z;
                s2TT0 = G0.w + G1.w + G2_.w + G3.w + R8.w;
                s2I1  = s2I0  - R0.x + R9.x;
                s2T1  = s2T0  - R0.y + R9.y;
                s2II1 = s2II0 - R0.z + R9.z;
                s2TT1 = s2TT0 - R0.w + R9.w;
                const float itg = g2B[wo][p0] + g2B[wo][p0 + 1]
                                + g2B[wo][p0 + 2] + g2B[wo][p0 + 3];
                s2IT0 = itg + wB[wo][hb + 8];
                s2IT1 = s2IT0 - wB[wo][hb] + wB[wo][hb + 9];
            } else {
                s2I0 = s2T0 = s2II0 = s2TT0 = s2IT0 = 0.f;
                s2I1 = s2T1 = s2II1 = s2TT1 = s2IT1 = 0.f;
            }

            rnI[0]  += s2I0  - rgI[0][j];  rgI[0][j]  = s2I0;
            rnT[0]  += s2T0  - rgT[0][j];  rgT[0][j]  = s2T0;
            rnII[0] += s2II0 - rgII[0][j]; rgII[0][j] = s2II0;
            rnTT[0] += s2TT0 - rgTT[0][j]; rgTT[0][j] = s2TT0;
            rnIT[0] += s2IT0 - rgIT[0][j]; rgIT[0][j] = s2IT0;
            rnI[1]  += s2I1  - rgI[1][j];  rgI[1][j]  = s2I1;
            rnT[1]  += s2T1  - rgT[1][j];  rgT[1][j]  = s2T1;
            rnII[1] += s2II1 - rgII[1][j]; rgII[1][j] = s2II1;
            rnTT[1] += s2TT1 - rgTT[1][j]; rgTT[1][j] = s2TT1;
            rnIT[1] += s2IT1 - rgIT[1][j]; rgIT[1][j] = s2IT1;

            if ((s >= d0 + 4) && ((s - 4) < dEnd)) {
                float cr, vv, tvv;
                cr  = rnIT[0] - rnI[0] * rnT[0] * INV_K;
                vv  = rnII[0] - rnI[0] * rnI[0] * INV_K;
                tvv = rnTT[0] - rnT[0] * rnT[0] * INV_K;
                acc += cr * cr * __builtin_amdgcn_rcpf(fmaf(tvv, vv, 1e-5f));
                cr  = rnIT[1] - rnI[1] * rnT[1] * INV_K;
                vv  = rnII[1] - rnI[1] * rnI[1] * INV_K;
                tvv = rnTT[1] - rnT[1] * rnT[1] * INV_K;
                acc += cr * cr * __builtin_amdgcn_rcpf(fmaf(tvv, vv, 1e-5f));
            }

            // ---- certify own glds for slice s+1 landed (s+2's stay in flight) ----
            asm volatile("s_waitcnt lgkmcnt(0)" ::: "memory");
            asm volatile("s_waitcnt vmcnt(2)" ::: "memory");
            __builtin_amdgcn_s_barrier();
            cur ^= 1;
        }
    }

    // ---- block reduction ----
#pragma unroll
    for (int off = 32; off > 0; off >>= 1) acc += __shfl_down(acc, off, 64);
    if (lane == 0) red[wid] = acc;
    __syncthreads();
    if (tid == 0) {
        const float bs = red[0] + red[1] + red[2] + red[3];
        atomicAdd(out, bs * (float)(-1.0 / NTOT));
    }
}

extern "C" void kernel_launch(void* const* d_in, const int* in_sizes, int n_in,
                              void* d_out, int out_size, void* d_ws, size_t ws_size,
                              hipStream_t stream) {
    const float* I = (const float*)d_in[0];
    const float* T = (const float*)d_in[1];
    float* out = (float*)d_out;
    float* ws  = (float*)d_ws;

    init_kernel<<<dim3(1), dim3(1), 0, stream>>>(out, ws);

    dim3 grid(DIM_W / TW, DIM_H / TH, DIM_B * NCH); // 10 x 6 x 18 = 1080
    dim3 block(256);
    lncc3d_kernel<<<grid, block, 0, stream>>>(I, T, ws, out);
}

// Round 10
// 82.350 us; speedup vs baseline: 1.2587x; 1.1021x over previous
//
#include <hip/hip_runtime.h>

#define DIM_W 160
#define DIM_H 192
#define DIM_D 160
#define DIM_B 2

constexpr int TW = 16;      // output tile width
constexpr int TH = 32;      // output tile height (P=2 px/thread in H)
constexpr int CH = 19;      // depth outputs per chunk (27 slices = 3 x 9)
constexpr int NCH = 9;      // ceil(160/19)
constexpr int RH = TH + 8;  // 40 region rows
constexpr float INV_K = 1.0f / 729.0f;
constexpr double NTOT = 9830400.0;

typedef unsigned int u32;
typedef __attribute__((address_space(1))) const u32 gu32;
typedef __attribute__((address_space(3))) u32 lu32;

__global__ void init_kernel(float* out, float* ws) {
    out[0] = 0.0f;
    ws[0] = 0.0f; ws[1] = 0.0f; ws[2] = 0.0f; ws[3] = 0.0f;
}

__device__ __forceinline__ int clampD(int s) {
    return s < 0 ? 0 : (s > DIM_D - 1 ? DIM_D - 1 : s);
}

__global__ __launch_bounds__(256)
void lncc3d_kernel(const float* __restrict__ I,
                   const float* __restrict__ T,
                   const float* __restrict__ zsrc,
                   float* __restrict__ out)
{
    // slice region, glds-staged: [buf][field][row][32 words]. Row = 128B.
    // logical f4 q of row r stored at physical f4 (q + 2r) & 7 (source-side
    // rotation). 2r (not r!): 16-lane phase (r0..r0+3, g0..g3) then hits each
    // bank-quad (2r+g+c) mod 8 exactly twice -> conflict-free b128 reads.
    __shared__ __align__(16) float sR[2][2][RH][32];
    // W-sums (I,T,II,TT): float4, column rotated (c+row)&15 (2-way = free)
    __shared__ __align__(16) float4 wA[RH][16];
    // W-sums IT, transposed [w][row], stride 44 (2-way = free)
    __shared__ __align__(16) float  wB[16][44];
    __shared__ float red[4];

    const int tid  = threadIdx.x;
    const int lane = tid & 63;
    const int wid  = tid >> 6;
    const int wo   = tid & 15;
    const int hb   = (tid >> 4) << 1;

    const int bw = blockIdx.x, bh = blockIdx.y, bz = blockIdx.z;
    const int b  = bz / NCH;
    const int c  = bz - b * NCH;
    const int w0 = bw * TW, h0 = bh * TH, d0 = c * CH;
    const int dEnd = min(d0 + CH, DIM_D);

    const int plane = DIM_H * DIM_W;
    const int fld  = wid >> 1;            // 0: field I, 1: field T
    const int kodd = wid & 1;             // chunk set {1,3} vs {0,2,4}
    const int nck  = kodd ? 2 : 3;        // glds per wave per slice
    const float* Fb = (fld ? T : I) + (size_t)b * DIM_D * plane;

    // per-lane glds source offsets (2r rotation folded into source address)
    int boff[3], crw[3];
#pragma unroll
    for (int i = 0; i < 3; ++i) {
        const int ck  = kodd ? (2 * i + 1) : (2 * i);
        const int row = 8 * ck + (lane >> 3);
        const int pf4 = lane & 7;
        const int lf4 = (pf4 - 2 * row) & 7;
        const int gh  = h0 - 4 + row;
        const int gw  = w0 - 8 + (lf4 << 2);
        crw[i]  = 8 * ck;
        boff[i] = (i < nck && gh >= 0 && gh < DIM_H && gw >= 0 && gw <= DIM_W - 4)
                  ? (gh * DIM_W + gw) : -1;
    }

    auto issue = [&](int sc, int buf) {
        const float* Fs = Fb + (size_t)sc * plane;
#pragma unroll
        for (int i = 0; i < 3; ++i) {
            if (i < nck) {
                const float* gp = (boff[i] >= 0) ? (Fs + boff[i]) : zsrc;
                __builtin_amdgcn_global_load_lds((gu32*)gp, (lu32*)&sR[buf][fld][crw[i]][0],
                                                 16, 0, 0);
            }
        }
    };

    // D-rings (slot = static J) + running sums, 5 fields x 2 px
    float rgI[2][9], rgT[2][9], rgII[2][9], rgTT[2][9], rgIT[2][9];
    float rnI[2], rnT[2], rnII[2], rnTT[2], rnIT[2];
#pragma unroll
    for (int p = 0; p < 2; ++p) {
        rnI[p] = rnT[p] = rnII[p] = rnTT[p] = rnIT[p] = 0.0f;
#pragma unroll
        for (int q = 0; q < 9; ++q) {
            rgI[p][q] = rgT[p][q] = rgII[p][q] = rgTT[p][q] = rgIT[p][q] = 0.0f;
        }
    }
    float acc = 0.0f;

    const int sStart = d0 - 4;
    int cur = 0;

    // ---- prologue: stage sStart -> buf0, sStart+1 -> buf1 ----
    issue(clampD(sStart), 0);
    issue(clampD(sStart + 1), 1);
    // certify own glds for sStart done (leave sStart+1's in flight), then publish
    if (kodd) { asm volatile("s_waitcnt vmcnt(2)" ::: "memory"); }
    else      { asm volatile("s_waitcnt vmcnt(3)" ::: "memory"); }
    __builtin_amdgcn_s_barrier();

    for (int t = 0; t < 3; ++t) {
        const int t9 = t * 9;
#pragma unroll
        for (int j = 0; j < 9; ++j) {
            const int s  = sStart + t9 + j;
            const bool vs = (s >= 0) && (s < DIM_D);

            // ---- stage 1: 9-wide W sums on sR[cur] ----
            if (vs && tid < 160) {
                const int r = tid >> 2;
                const int g = tid & 3;
                const float* rIp = &sR[cur][0][r][0];
                const float* rTp = &sR[cur][1][r][0];
                const int q0 = ((g + 1 + 2 * r) & 7) << 2;
                const int q1 = ((g + 2 + 2 * r) & 7) << 2;
                const int q2 = ((g + 3 + 2 * r) & 7) << 2;
                const float4 ia  = *(const float4*)(rIp + q0);
                const float4 ib4 = *(const float4*)(rIp + q1);
                const float4 ic4 = *(const float4*)(rIp + q2);
                const float4 ta  = *(const float4*)(rTp + q0);
                const float4 tb4 = *(const float4*)(rTp + q1);
                const float4 tc4 = *(const float4*)(rTp + q2);
                const float iv[12] = {ia.x, ia.y, ia.z, ia.w, ib4.x, ib4.y, ib4.z, ib4.w,
                                      ic4.x, ic4.y, ic4.z, ic4.w};
                const float tv[12] = {ta.x, ta.y, ta.z, ta.w, tb4.x, tb4.y, tb4.z, tb4.w,
                                      tc4.x, tc4.y, tc4.z, tc4.w};
                float aI = 0.f, aT = 0.f, aII = 0.f, aTT = 0.f, aIT = 0.f;
#pragma unroll
                for (int k = 0; k < 9; ++k) {
                    aI += iv[k]; aT += tv[k];
                    aII = fmaf(iv[k], iv[k], aII);
                    aTT = fmaf(tv[k], tv[k], aTT);
                    aIT = fmaf(iv[k], tv[k], aIT);
                }
                const int c0 = g << 2;
                wA[r][(c0 + r) & 15] = make_float4(aI, aT, aII, aTT);
                wB[c0][r] = aIT;
#pragma unroll
                for (int q = 1; q < 4; ++q) {
                    const float ni = iv[8 + q], oi = iv[q - 1];
                    const float nt = tv[8 + q], ot = tv[q - 1];
                    aI += ni - oi; aT += nt - ot;
                    aII = fmaf(ni, ni, fmaf(oi, -oi, aII));
                    aTT = fmaf(nt, nt, fmaf(ot, -ot, aTT));
                    aIT = fmaf(ni, nt, fmaf(oi, -ot, aIT));
                    wA[r][(c0 + q + r) & 15] = make_float4(aI, aT, aII, aTT);
                    wB[c0 + q][r] = aIT;
                }
            }
            asm volatile("s_waitcnt lgkmcnt(0)" ::: "memory");
            __builtin_amdgcn_s_barrier();   // wA/wB published; sR[cur] reads done

            // ---- issue glds for slice s+2 into sR[cur] (safe: readers done) ----
            issue(clampD(s + 2), cur);

            // ---- stage 2: 9-tall H sums (2 px), rings slot j, emit ----
            float s2I0, s2T0, s2II0, s2TT0, s2IT0, s2I1, s2T1, s2II1, s2TT1, s2IT1;
            if (vs) {
                const float4 A0 = wA[hb][(wo + hb) & 15];
                float sx = A0.x, sy = A0.y, szv = A0.z, swv = A0.w;
#pragma unroll
                for (int k = 1; k < 9; ++k) {
                    const float4 Ak = wA[hb + k][(wo + hb + k) & 15];
                    sx += Ak.x; sy += Ak.y; szv += Ak.z; swv += Ak.w;
                }
                const float4 A9 = wA[hb + 9][(wo + hb + 9) & 15];
                const float2 B0 = *(const float2*)&wB[wo][hb];
                const float2 B1 = *(const float2*)&wB[wo][hb + 2];
                const float2 B2 = *(const float2*)&wB[wo][hb + 4];
                const float2 B3 = *(const float2*)&wB[wo][hb + 6];
                const float2 B4 = *(const float2*)&wB[wo][hb + 8];
                const float sbv = B0.x + B0.y + B1.x + B1.y + B2.x + B2.y
                                + B3.x + B3.y + B4.x;
                s2I0 = sx; s2T0 = sy; s2II0 = szv; s2TT0 = swv; s2IT0 = sbv;
                s2I1  = sx  - A0.x + A9.x;
                s2T1  = sy  - A0.y + A9.y;
                s2II1 = szv - A0.z + A9.z;
                s2TT1 = swv - A0.w + A9.w;
                s2IT1 = sbv - B0.x + B4.y;
            } else {
                s2I0 = s2T0 = s2II0 = s2TT0 = s2IT0 = 0.f;
                s2I1 = s2T1 = s2II1 = s2TT1 = s2IT1 = 0.f;
            }

            rnI[0]  += s2I0  - rgI[0][j];  rgI[0][j]  = s2I0;
            rnT[0]  += s2T0  - rgT[0][j];  rgT[0][j]  = s2T0;
            rnII[0] += s2II0 - rgII[0][j]; rgII[0][j] = s2II0;
            rnTT[0] += s2TT0 - rgTT[0][j]; rgTT[0][j] = s2TT0;
            rnIT[0] += s2IT0 - rgIT[0][j]; rgIT[0][j] = s2IT0;
            rnI[1]  += s2I1  - rgI[1][j];  rgI[1][j]  = s2I1;
            rnT[1]  += s2T1  - rgT[1][j];  rgT[1][j]  = s2T1;
            rnII[1] += s2II1 - rgII[1][j]; rgII[1][j] = s2II1;
            rnTT[1] += s2TT1 - rgTT[1][j]; rgTT[1][j] = s2TT1;
            rnIT[1] += s2IT1 - rgIT[1][j]; rgIT[1][j] = s2IT1;

            if ((s >= d0 + 4) && ((s - 4) < dEnd)) {
                float cr, vv, tvv;
                cr  = rnIT[0] - rnI[0] * rnT[0] * INV_K;
                vv  = rnII[0] - rnI[0] * rnI[0] * INV_K;
                tvv = rnTT[0] - rnT[0] * rnT[0] * INV_K;
                acc += cr * cr * __builtin_amdgcn_rcpf(fmaf(tvv, vv, 1e-5f));
                cr  = rnIT[1] - rnI[1] * rnT[1] * INV_K;
                vv  = rnII[1] - rnI[1] * rnI[1] * INV_K;
                tvv = rnTT[1] - rnT[1] * rnT[1] * INV_K;
                acc += cr * cr * __builtin_amdgcn_rcpf(fmaf(tvv, vv, 1e-5f));
            }

            // ---- certify own glds for slice s+1 landed (s+2's stay in flight) ----
            asm volatile("s_waitcnt lgkmcnt(0)" ::: "memory");
            if (kodd) { asm volatile("s_waitcnt vmcnt(2)" ::: "memory"); }
            else      { asm volatile("s_waitcnt vmcnt(3)" ::: "memory"); }
            __builtin_amdgcn_s_barrier();
            cur ^= 1;
        }
    }

    // ---- block reduction ----
#pragma unroll
    for (int off = 32; off > 0; off >>= 1) acc += __shfl_down(acc, off, 64);
    if (lane == 0) red[wid] = acc;
    __syncthreads();
    if (tid == 0) {
        const float bs = red[0] + red[1] + red[2] + red[3];
        atomicAdd(out, bs * (float)(-1.0 / NTOT));
    }
}

extern "C" void kernel_launch(void* const* d_in, const int* in_sizes, int n_in,
                              void* d_out, int out_size, void* d_ws, size_t ws_size,
                              hipStream_t stream) {
    const float* I = (const float*)d_in[0];
    const float* T = (const float*)d_in[1];
    float* out = (float*)d_out;
    float* ws  = (float*)d_ws;

    init_kernel<<<dim3(1), dim3(1), 0, stream>>>(out, ws);

    dim3 grid(DIM_W / TW, DIM_H / TH, DIM_B * NCH); // 10 x 6 x 18 = 1080
    dim3 block(256);
    lncc3d_kernel<<<grid, block, 0, stream>>>(I, T, ws, out);
}